// Round 4
// baseline (11398.576 us; speedup 1.0000x reference)
//
#include <hip/hip_runtime.h>
#include <stdint.h>

// ---------------------------------------------------------------------------
// MRT seq2seq sampler for MI355X. Round 4: resubmit fp32-exact correctness
// anchor unchanged (rounds 0-3 all died in infra: acquisition timeout /
// container failure - zero on-device signal so far; no evidence to act on).
// Sizes (fixed by problem): V=16000 E=512 H=512 S=24 T=26 B=2 N=100 BN=200
// MAX_LEN-1 = 37 decode steps.
// RNG: JAX threefry2x32, threefry_partitionable=True semantics.
// ---------------------------------------------------------------------------

#define DINLINE __device__ __forceinline__

DINLINE uint32_t rotl32(uint32_t x, int r) { return (x << r) | (x >> (32 - r)); }

// JAX threefry2x32 (jax/_src/prng.py), 20 rounds.
DINLINE void tf2x32(uint32_t k0, uint32_t k1, uint32_t x0, uint32_t x1,
                    uint32_t& y0, uint32_t& y1)
{
  const uint32_t ks2 = k0 ^ k1 ^ 0x1BD11BDAu;
#define TFR(r) { x0 += x1; x1 = rotl32(x1, r); x1 ^= x0; }
  x0 += k0; x1 += k1;
  TFR(13) TFR(15) TFR(26) TFR(6)
  x0 += k1; x1 += ks2 + 1u;
  TFR(17) TFR(29) TFR(16) TFR(24)
  x0 += ks2; x1 += k0 + 2u;
  TFR(13) TFR(15) TFR(26) TFR(6)
  x0 += k0; x1 += k1 + 3u;
  TFR(17) TFR(29) TFR(16) TFR(24)
  x0 += k1; x1 += ks2 + 4u;
  TFR(13) TFR(15) TFR(26) TFR(6)
  x0 += ks2; x1 += k0 + 5u;
#undef TFR
  y0 = x0; y1 = x1;
}

// partitionable random_bits (32-bit): counter = (hi=0, lo=flat), bits = y0^y1
// then uniform(minval=tiny,1) -> gumbel, matching jax gumbel()/uniform() fp32.
DINLINE float gumbel32(uint32_t k0, uint32_t k1, uint32_t flat)
{
  uint32_t b1, b2; tf2x32(k0, k1, 0u, flat, b1, b2);
  const uint32_t bits = b1 ^ b2;
  const float f = __uint_as_float((bits >> 9) | 0x3F800000u) - 1.0f;
  const float u = (f == 0.0f) ? 1.17549435e-38f : f; // max(tiny, f*1+tiny)
  return -logf(-logf(u));
}

DINLINE float sigmoidf_(float x) { return 1.0f / (1.0f + expf(-x)); }

// ---------------------------------------------------------------------------
// init: zero encoder h0
__global__ void k_init(float* __restrict__ henc0)
{
  const int i = blockIdx.x * 256 + threadIdx.x;
  if (i < 1024) henc0[i] = 0.0f;
}

// ---------------------------------------------------------------------------
// Encoder: xg[s*2+b][g] = emb_src[src[s][b]] @ Wex + be   (48 x 1536, K=512)
__global__ __launch_bounds__(256) void k_enc_xg(
    const int* __restrict__ src, const float* __restrict__ emb,
    const float* __restrict__ Wex, const float* __restrict__ be,
    float* __restrict__ xg)
{
  __shared__ float xl[512];
  const int rrow = blockIdx.x;         // s*2+b
  const int tid = threadIdx.x;
  const int tokv = src[rrow];
  for (int i = tid; i < 512; i += 256) xl[i] = emb[(size_t)tokv * 512 + i];
  __syncthreads();
  const int j = blockIdx.y * 256 + tid;
  float a = be[j];
  for (int k = 0; k < 512; ++k) a += xl[k] * Wex[(size_t)k * 1536 + j];
  xg[(size_t)rrow * 1536 + j] = a;
}

// Encoder recurrent step: hout = GRU(x_s, hprev). grid(4) x 256, 2 rows x 128 j.
__global__ __launch_bounds__(256) void k_enc_step(
    const float* __restrict__ hprev, const float* __restrict__ xg,
    const float* __restrict__ Weh, float* __restrict__ hout)
{
  __shared__ float hp[2][512];
  const int tid = threadIdx.x;
  for (int i = tid; i < 1024; i += 256) hp[i >> 9][i & 511] = hprev[i];
  __syncthreads();
  const int row = tid >> 7;                       // 0..1
  const int j = blockIdx.x * 128 + (tid & 127);   // 0..511
  float gz = 0.f, gr = 0.f, gn = 0.f;
  for (int k = 0; k < 512; ++k) {
    const float h = hp[row][k];
    const float* w = Weh + (size_t)k * 1536 + j;
    gz += h * w[0]; gr += h * w[512]; gn += h * w[1024];
  }
  const float xz = xg[row * 1536 + j];
  const float xr = xg[row * 1536 + j + 512];
  const float xn = xg[row * 1536 + j + 1024];
  const float z = sigmoidf_(xz + gz);
  const float r = sigmoidf_(xr + gr);
  const float n = tanhf(xn + r * gn);
  hout[row * 512 + j] = (1.0f - z) * n + z * hp[row][j];
}

// Decoder state init: h = repeat(hT), tok=BOS, dead=0, acc=0, match=1 (BOS hit)
__global__ void k_dec_init(const float* __restrict__ ctx23, float* __restrict__ hA,
                           int* __restrict__ tok, float* __restrict__ dead,
                           float* __restrict__ acc, int* __restrict__ mc)
{
  const int i = blockIdx.x * 256 + threadIdx.x;
  if (i < 200 * 512) {
    const int bn = i >> 9, k = i & 511, b = bn / 100;
    hA[i] = ctx23[b * 512 + k];
  }
  if (i < 200) { tok[i] = 2; dead[i] = 0.f; acc[i] = 0.f; mc[i] = 1; }
}

// ---------------------------------------------------------------------------
// gates GEMM: z=0 -> gx = emb_tgt[tok] @ Wdx + bd ; z=1 -> gh = h @ Wdh
// tiles 32x32, BK=32, 2x2 microtile. grid(48, 7, 2) x 256.
__global__ __launch_bounds__(256) void k_gates(
    const float* __restrict__ hprev, const float* __restrict__ emb_tgt,
    const int* __restrict__ tok,
    const float* __restrict__ Wdx, const float* __restrict__ Wdh,
    const float* __restrict__ bd,
    float* __restrict__ gx, float* __restrict__ gh)
{
  __shared__ float As[32][33];
  __shared__ float Ws[32][32];
  const int tid = threadIdx.x;
  const int nt = blockIdx.x, mt = blockIdx.y, zz = blockIdx.z;
  const int c0 = nt * 32;
  const float* __restrict__ Bw = zz ? Wdh : Wdx;
  float a00 = 0.f, a01 = 0.f, a10 = 0.f, a11 = 0.f;
  const int tr = tid >> 4, tc = tid & 15;
  for (int k0 = 0; k0 < 512; k0 += 32) {
    {
      const int r = tid >> 3, kk = (tid & 7) << 2;
      const int row = mt * 32 + r;
      float4 v = make_float4(0.f, 0.f, 0.f, 0.f);
      if (row < 200) {
        const int k = k0 + kk;
        if (zz == 0) v = *(const float4*)(emb_tgt + (size_t)tok[row] * 512 + k);
        else         v = *(const float4*)(hprev + (size_t)row * 512 + k);
      }
      As[kk + 0][r] = v.x; As[kk + 1][r] = v.y; As[kk + 2][r] = v.z; As[kk + 3][r] = v.w;
    }
    {
      const int kr = tid >> 3, cc = (tid & 7) << 2;
      *(float4*)&Ws[kr][cc] = *(const float4*)(Bw + (size_t)(k0 + kr) * 1536 + c0 + cc);
    }
    __syncthreads();
#pragma unroll
    for (int kk = 0; kk < 32; ++kk) {
      const float a0 = As[kk][tr * 2], a1 = As[kk][tr * 2 + 1];
      const float w0 = Ws[kk][tc * 2], w1 = Ws[kk][tc * 2 + 1];
      a00 += a0 * w0; a01 += a0 * w1; a10 += a1 * w0; a11 += a1 * w1;
    }
    __syncthreads();
  }
  float* __restrict__ outp = zz ? gh : gx;
  const int row0 = mt * 32 + tr * 2, col0 = c0 + tc * 2;
  const float b0 = zz ? 0.f : bd[col0];
  const float b1 = zz ? 0.f : bd[col0 + 1];
  if (row0 < 200) {
    outp[(size_t)row0 * 1536 + col0]     = a00 + b0;
    outp[(size_t)row0 * 1536 + col0 + 1] = a01 + b1;
  }
  if (row0 + 1 < 200) {
    outp[(size_t)(row0 + 1) * 1536 + col0]     = a10 + b0;
    outp[(size_t)(row0 + 1) * 1536 + col0 + 1] = a11 + b1;
  }
}

// ---------------------------------------------------------------------------
// Per-row: GRU combine -> h_t, then attention softmax over S=24 -> context c.
// grid(200) x 256.
__global__ __launch_bounds__(256) void k_update_attn(
    const float* __restrict__ gx, const float* __restrict__ gh,
    const float* __restrict__ hprev, float* __restrict__ hcur,
    const float* __restrict__ ctx, const int* __restrict__ src,
    float* __restrict__ cc)
{
  const int bn = blockIdx.x, b = bn / 100;
  const int tid = threadIdx.x;
  __shared__ float hn[512];
  __shared__ float sc[24];
  const float* gxr = gx + (size_t)bn * 1536;
  const float* ghr = gh + (size_t)bn * 1536;
  const float* hpr = hprev + (size_t)bn * 512;
  for (int j = tid; j < 512; j += 256) {
    const float z = sigmoidf_(gxr[j] + ghr[j]);
    const float r = sigmoidf_(gxr[j + 512] + ghr[j + 512]);
    const float n = tanhf(gxr[j + 1024] + r * ghr[j + 1024]);
    const float h = (1.0f - z) * n + z * hpr[j];
    hn[j] = h;
    hcur[(size_t)bn * 512 + j] = h;
  }
  __syncthreads();
  const int w = tid >> 6, lane = tid & 63;
  for (int s = w; s < 24; s += 4) {
    const float* cr = ctx + (size_t)(s * 2 + b) * 512;
    float v = 0.f;
#pragma unroll
    for (int m = 0; m < 8; ++m) { const int k = lane + 64 * m; v += hn[k] * cr[k]; }
#pragma unroll
    for (int m2 = 32; m2 >= 1; m2 >>= 1) v += __shfl_xor(v, m2, 64);
    if (lane == 0) sc[s] = (src[s * 2 + b] == 0) ? -1e9f : v;  // pad mask (NEG_INF)
  }
  __syncthreads();
  float mx = -3.0e38f;
#pragma unroll
  for (int s = 0; s < 24; ++s) mx = fmaxf(mx, sc[s]);
  float ez[24]; float sum = 0.f;
#pragma unroll
  for (int s = 0; s < 24; ++s) { ez[s] = expf(sc[s] - mx); sum += ez[s]; }
#pragma unroll
  for (int s = 0; s < 24; ++s) ez[s] = ez[s] / sum;  // attn, rounded like reference
  for (int j = tid; j < 512; j += 256) {
    float a = 0.f;
#pragma unroll
    for (int s = 0; s < 24; ++s) a += ez[s] * ctx[(size_t)(s * 2 + b) * 512 + j];
    cc[(size_t)bn * 512 + j] = a;
  }
}

// ---------------------------------------------------------------------------
// o = tanh([h|c] @ Wo + bo). tiles 32x32, K=1024. grid(16, 7) x 256.
__global__ __launch_bounds__(256) void k_oproj(
    const float* __restrict__ hcur, const float* __restrict__ ccx,
    const float* __restrict__ Wo, const float* __restrict__ bo,
    float* __restrict__ ob)
{
  __shared__ float As[32][33];
  __shared__ float Ws[32][32];
  const int tid = threadIdx.x;
  const int nt = blockIdx.x, mt = blockIdx.y;
  const int c0 = nt * 32;
  float a00 = 0.f, a01 = 0.f, a10 = 0.f, a11 = 0.f;
  const int tr = tid >> 4, tc = tid & 15;
  for (int k0 = 0; k0 < 1024; k0 += 32) {
    {
      const int r = tid >> 3, kk = (tid & 7) << 2;
      const int row = mt * 32 + r;
      float4 v = make_float4(0.f, 0.f, 0.f, 0.f);
      if (row < 200) {
        const int k = k0 + kk;
        const float* s = (k < 512) ? (hcur + (size_t)row * 512 + k)
                                   : (ccx + (size_t)row * 512 + (k - 512));
        v = *(const float4*)s;
      }
      As[kk + 0][r] = v.x; As[kk + 1][r] = v.y; As[kk + 2][r] = v.z; As[kk + 3][r] = v.w;
    }
    {
      const int kr = tid >> 3, cc = (tid & 7) << 2;
      *(float4*)&Ws[kr][cc] = *(const float4*)(Wo + (size_t)(k0 + kr) * 512 + c0 + cc);
    }
    __syncthreads();
#pragma unroll
    for (int kk = 0; kk < 32; ++kk) {
      const float a0 = As[kk][tr * 2], a1 = As[kk][tr * 2 + 1];
      const float w0 = Ws[kk][tc * 2], w1 = Ws[kk][tc * 2 + 1];
      a00 += a0 * w0; a01 += a0 * w1; a10 += a1 * w0; a11 += a1 * w1;
    }
    __syncthreads();
  }
  const int row0 = mt * 32 + tr * 2, col0 = c0 + tc * 2;
  if (row0 < 200) {
    ob[(size_t)row0 * 512 + col0]     = tanhf(a00 + bo[col0]);
    ob[(size_t)row0 * 512 + col0 + 1] = tanhf(a01 + bo[col0 + 1]);
  }
  if (row0 + 1 < 200) {
    ob[(size_t)(row0 + 1) * 512 + col0]     = tanhf(a10 + bo[col0]);
    ob[(size_t)(row0 + 1) * 512 + col0 + 1] = tanhf(a11 + bo[col0 + 1]);
  }
}

// ---------------------------------------------------------------------------
// logits = o @ Wg + bg, fused gumbel + per-tile argmax / max / sumexp partials.
// tiles 64x64, BK=32, 4x4 microtile. grid(250, 4) x 256. Never stores logits.
__global__ __launch_bounds__(256) void k_gemm_logits(
    const float* __restrict__ Ao, const float* __restrict__ Wg,
    const float* __restrict__ bg, int t,
    float* __restrict__ p_bv, float* __restrict__ p_bl,
    float* __restrict__ p_ml, float* __restrict__ p_se, int* __restrict__ p_bi)
{
  __shared__ float As[32][68];
  __shared__ float Ws[32][64];
  const int tid = threadIdx.x;
  const int nt = blockIdx.x, mt = blockIdx.y;
  const int c0 = nt * 64;
  float acc[4][4] = {};
  const int tr = tid >> 4, tc = tid & 15;
  for (int k0 = 0; k0 < 512; k0 += 32) {
    {
      const int r = tid >> 2, kk = (tid & 3) << 3;
      const int row = mt * 64 + r;
      float4 v0 = make_float4(0.f, 0.f, 0.f, 0.f), v1 = v0;
      if (row < 200) {
        const float* s = Ao + (size_t)row * 512 + k0 + kk;
        v0 = *(const float4*)s; v1 = *(const float4*)(s + 4);
      }
      As[kk + 0][r] = v0.x; As[kk + 1][r] = v0.y; As[kk + 2][r] = v0.z; As[kk + 3][r] = v0.w;
      As[kk + 4][r] = v1.x; As[kk + 5][r] = v1.y; As[kk + 6][r] = v1.z; As[kk + 7][r] = v1.w;
    }
    {
      const int kr = tid >> 3, cc = (tid & 7) << 3;
      const float* s = Wg + (size_t)(k0 + kr) * 16000 + c0 + cc;
      *(float4*)&Ws[kr][cc]     = *(const float4*)s;
      *(float4*)&Ws[kr][cc + 4] = *(const float4*)(s + 4);
    }
    __syncthreads();
#pragma unroll
    for (int kk = 0; kk < 32; ++kk) {
      const float4 a = *(const float4*)&As[kk][tr << 2];
      const float4 w = *(const float4*)&Ws[kk][tc << 2];
      acc[0][0] += a.x * w.x; acc[0][1] += a.x * w.y; acc[0][2] += a.x * w.z; acc[0][3] += a.x * w.w;
      acc[1][0] += a.y * w.x; acc[1][1] += a.y * w.y; acc[1][2] += a.y * w.z; acc[1][3] += a.y * w.w;
      acc[2][0] += a.z * w.x; acc[2][1] += a.z * w.y; acc[2][2] += a.z * w.z; acc[2][3] += a.z * w.w;
      acc[3][0] += a.w * w.x; acc[3][1] += a.w * w.y; acc[3][2] += a.w * w.z; acc[3][3] += a.w * w.w;
    }
    __syncthreads();
  }
  // epilogue: gumbel + per-row tile reductions over the 64-col tile
  uint32_t sk0, sk1; tf2x32(0u, 42u, 0u, (uint32_t)t, sk0, sk1); // split(key(42))[t]
  const float NEGINF = -3.0e38f;
#pragma unroll
  for (int i = 0; i < 4; ++i) {
    const int row = mt * 64 + (tr << 2) + i;
    const bool valid = (row < 200);
    float logit[4];
    float tmax = NEGINF;
#pragma unroll
    for (int j = 0; j < 4; ++j) {
      const int col = c0 + (tc << 2) + j;
      logit[j] = acc[i][j] + bg[col];
      tmax = fmaxf(tmax, logit[j]);
    }
    if (!valid) tmax = NEGINF;
#pragma unroll
    for (int m = 1; m <= 8; m <<= 1) tmax = fmaxf(tmax, __shfl_xor(tmax, m, 64));
    float se = 0.f, bv = NEGINF, bl = 0.f; int bi = 0;
    if (valid) {
#pragma unroll
      for (int j = 0; j < 4; ++j) {
        const int col = c0 + (tc << 2) + j;
        se += expf(logit[j] - tmax);
        const float g = gumbel32(sk0, sk1, (uint32_t)(row * 16000 + col));
        const float v = logit[j] + g;
        if (v > bv) { bv = v; bi = col; bl = logit[j]; }  // first-occurrence ties
      }
    }
#pragma unroll
    for (int m = 1; m <= 8; m <<= 1) {
      const float ov = __shfl_xor(bv, m, 64);
      const int   oi = __shfl_xor(bi, m, 64);
      const float ol = __shfl_xor(bl, m, 64);
      se += __shfl_xor(se, m, 64);
      if (ov > bv || (ov == bv && oi < bi)) { bv = ov; bi = oi; bl = ol; }
    }
    if (tc == 0 && valid) {
      const size_t p = (size_t)nt * 200 + row;
      p_bv[p] = bv; p_bl[p] = bl; p_ml[p] = tmax; p_se[p] = se; p_bi[p] = bi;
    }
  }
}

// ---------------------------------------------------------------------------
// Combine 250 tile-partials per row: sample token, update acc/dead/tok/match.
// grid(4) x 64.
__global__ void k_reduce_sample(
    const float* __restrict__ p_bv, const float* __restrict__ p_bl,
    const float* __restrict__ p_ml, const float* __restrict__ p_se,
    const int* __restrict__ p_bi,
    const int* __restrict__ tgt, int t,
    int* __restrict__ tok, float* __restrict__ dead,
    float* __restrict__ acc, int* __restrict__ mc)
{
  const int bn = blockIdx.x * 64 + threadIdx.x;
  if (bn >= 200) return;
  float runM = -3.0e38f, runS = 0.f, bv = -3.0e38f, bl = 0.f;
  int bi = 0;
  for (int nt = 0; nt < 250; ++nt) {
    const size_t p = (size_t)nt * 200 + bn;
    const float m = p_ml[p], s = p_se[p];
    if (m > runM) { runS = runS * expf(runM - m) + s; runM = m; }
    else          { runS += s * expf(m - runM); }
    const float v = p_bv[p];
    if (v > bv) { bv = v; bi = p_bi[p]; bl = p_bl[p]; }  // lower idx wins ties
  }
  // logp[nxt] = (logit - max) - log(sumexp), same association as jax log_softmax
  const float dv = dead[bn];
  const float sc = ((bl - runM) - logf(runS)) * (1.0f - dv);
  acc[bn] += sc;
  const int b = bn / 100;
  if (t + 1 < 26) {
    const int tv = tgt[(t + 1) * 2 + b];
    if (tv != 0 && bi == tv) mc[bn] += 1;
  }
  dead[bn] = fmaxf(dv, (bi == 3) ? 1.0f : 0.0f);  // EOS=3
  tok[bn] = bi;
}

// ---------------------------------------------------------------------------
// Final: bleu, per-batch softmax over N=100 of acc*ALPHA, 4 scalar outputs.
__global__ __launch_bounds__(256) void k_final(
    const float* __restrict__ accb, const int* __restrict__ mc,
    const int* __restrict__ tgt, float* __restrict__ out)
{
  __shared__ int ncw[4];
  __shared__ float LS[2], SS[2], QS[2];
  const int tid = threadIdx.x, w = tid >> 6, lane = tid & 63;
  int c0c = 0, c1c = 0;
  for (int tt = 0; tt < 26; ++tt) {
    c0c += (tgt[tt * 2] != 0);
    c1c += (tgt[tt * 2 + 1] != 0);
  }
  int nc = (tid < 200) ? mc[tid] : 0;
#pragma unroll
  for (int m = 32; m >= 1; m >>= 1) nc += __shfl_xor(nc, m, 64);
  if (lane == 0) ncw[w] = nc;
  if (w < 2) {
    const int b = w;
    const float denom = fmaxf((float)(b == 0 ? c0c : c1c), 1.0f);
    const float e0 = accb[b * 100 + lane] * 0.005f;
    const float e1 = (lane < 36) ? accb[b * 100 + 64 + lane] * 0.005f : -3.0e38f;
    float mx = fmaxf(e0, e1);
#pragma unroll
    for (int m = 32; m >= 1; m >>= 1) mx = fmaxf(mx, __shfl_xor(mx, m, 64));
    float S = 0.f, L = 0.f, Q = 0.f;
    {
      const float p = expf(e0 - mx);
      const float bl = (float)mc[b * 100 + lane] / denom;
      S += p; L += bl * p; Q += bl * bl * p;
    }
    if (lane < 36) {
      const float p = expf(e1 - mx);
      const float bl = (float)mc[b * 100 + 64 + lane] / denom;
      S += p; L += bl * p; Q += bl * bl * p;
    }
#pragma unroll
    for (int m = 32; m >= 1; m >>= 1) {
      S += __shfl_xor(S, m, 64);
      L += __shfl_xor(L, m, 64);
      Q += __shfl_xor(Q, m, 64);
    }
    if (lane == 0) { LS[b] = L; SS[b] = S; QS[b] = Q; }
  }
  __syncthreads();
  if (tid == 0) {
    out[0] = -(LS[0] / SS[0] + LS[1] / SS[1]);  // totalLoss
    out[1] =  QS[0] / SS[0] + QS[1] / SS[1];    // secondMoment
    out[2] = 100.0f * (float)(c0c + c1c);       // numWords
    out[3] = (float)(ncw[0] + ncw[1] + ncw[2] + ncw[3]);  // numCorrect
  }
}

// ---------------------------------------------------------------------------
extern "C" void kernel_launch(void* const* d_in, const int* in_sizes, int n_in,
                              void* d_out, int out_size, void* d_ws, size_t ws_size,
                              hipStream_t stream)
{
  (void)in_sizes; (void)n_in; (void)out_size; (void)ws_size;
  const int*   src     = (const int*)  d_in[0];
  const int*   tgt     = (const int*)  d_in[1];
  // d_in[2] lengths: unused by the reference math
  const float* emb_src = (const float*)d_in[3];
  const float* emb_tgt = (const float*)d_in[4];
  const float* Wex     = (const float*)d_in[5];
  const float* Weh     = (const float*)d_in[6];
  const float* be      = (const float*)d_in[7];
  const float* Wdx     = (const float*)d_in[8];
  const float* Wdh     = (const float*)d_in[9];
  const float* bd      = (const float*)d_in[10];
  const float* Wo      = (const float*)d_in[11];
  const float* bo      = (const float*)d_in[12];
  const float* Wg      = (const float*)d_in[13];
  const float* bg      = (const float*)d_in[14];
  float* out = (float*)d_out;

  float* W = (float*)d_ws;
  size_t off = 0;
  auto alloc = [&](size_t n) { float* p = W + off; off += n; return p; };
  float* henc0 = alloc(1024);
  float* xgE   = alloc(48 * 1536);
  float* ctx   = alloc(24 * 1024);
  float* hA    = alloc(200 * 512);
  float* hB    = alloc(200 * 512);
  float* gx    = alloc(200 * 1536);
  float* gh    = alloc(200 * 1536);
  float* cc    = alloc(200 * 512);
  float* ob    = alloc(200 * 512);
  float* p_bv  = alloc(250 * 200);
  float* p_bl  = alloc(250 * 200);
  float* p_ml  = alloc(250 * 200);
  float* p_se  = alloc(250 * 200);
  int*   p_bi  = (int*)alloc(250 * 200);
  int*   tok   = (int*)alloc(200);
  float* dead  = alloc(200);
  float* accb  = alloc(200);
  int*   mc    = (int*)alloc(200);
  // total ~5.5 MB of d_ws

  // --- encoder ---
  k_init<<<dim3(4), dim3(256), 0, stream>>>(henc0);
  k_enc_xg<<<dim3(48, 6), dim3(256), 0, stream>>>(src, emb_src, Wex, be, xgE);
  for (int s = 0; s < 24; ++s) {
    const float* hp = (s == 0) ? henc0 : (ctx + (size_t)(s - 1) * 1024);
    k_enc_step<<<dim3(4), dim3(256), 0, stream>>>(
        hp, xgE + (size_t)s * 2 * 1536, Weh, ctx + (size_t)s * 1024);
  }
  k_dec_init<<<dim3(400), dim3(256), 0, stream>>>(ctx + 23 * 1024, hA, tok, dead, accb, mc);

  // --- decoder: 37 sequential sampled steps ---
  for (int t = 0; t < 37; ++t) {
    float* hp = (t & 1) ? hB : hA;
    float* hc = (t & 1) ? hA : hB;
    k_gates<<<dim3(48, 7, 2), dim3(256), 0, stream>>>(hp, emb_tgt, tok, Wdx, Wdh, bd, gx, gh);
    k_update_attn<<<dim3(200), dim3(256), 0, stream>>>(gx, gh, hp, hc, ctx, src, cc);
    k_oproj<<<dim3(16, 7), dim3(256), 0, stream>>>(hc, cc, Wo, bo, ob);
    k_gemm_logits<<<dim3(250, 4), dim3(256), 0, stream>>>(ob, Wg, bg, t,
                                                          p_bv, p_bl, p_ml, p_se, p_bi);
    k_reduce_sample<<<dim3(4), dim3(64), 0, stream>>>(p_bv, p_bl, p_ml, p_se, p_bi,
                                                      tgt, t, tok, dead, accb, mc);
  }
  k_final<<<dim3(1), dim3(256), 0, stream>>>(accb, mc, tgt, out);
}

// Round 6
// 6545.041 us; speedup vs baseline: 1.7416x; 1.7416x over previous
//
#include <hip/hip_runtime.h>
#include <stdint.h>

// ---------------------------------------------------------------------------
// MRT seq2seq sampler for MI355X. Round 6: resubmit round-5 kernel unchanged
// (R5 died in infra before reaching hardware). R4 baseline: passed, absmax
// 0.0, 11.4 ms; counters showed k_reduce_sample = 147us x 37 = 5.4 ms
// (serial 250-iter dependent-load loop on 200 threads) and k_oproj at 0.55%
// occupancy. Fixes herein: (1) parallel tree-reduce for reduce_sample,
// bn-major partial layout (argmax path bit-exact; only softmax-denominator
// summation order changes ~1e-7); (2) k_oproj retiled to 16x32 tiles ->
// 208 blocks (per-output K-order unchanged -> bit-identical ob).
// k_gemm_logits arithmetic untouched (token-exactness anchor).
// RNG: JAX threefry2x32, threefry_partitionable=True semantics. VERIFIED r4.
// ---------------------------------------------------------------------------

#define DINLINE __device__ __forceinline__

DINLINE uint32_t rotl32(uint32_t x, int r) { return (x << r) | (x >> (32 - r)); }

// JAX threefry2x32 (jax/_src/prng.py), 20 rounds.
DINLINE void tf2x32(uint32_t k0, uint32_t k1, uint32_t x0, uint32_t x1,
                    uint32_t& y0, uint32_t& y1)
{
  const uint32_t ks2 = k0 ^ k1 ^ 0x1BD11BDAu;
#define TFR(r) { x0 += x1; x1 = rotl32(x1, r); x1 ^= x0; }
  x0 += k0; x1 += k1;
  TFR(13) TFR(15) TFR(26) TFR(6)
  x0 += k1; x1 += ks2 + 1u;
  TFR(17) TFR(29) TFR(16) TFR(24)
  x0 += ks2; x1 += k0 + 2u;
  TFR(13) TFR(15) TFR(26) TFR(6)
  x0 += k0; x1 += k1 + 3u;
  TFR(17) TFR(29) TFR(16) TFR(24)
  x0 += k1; x1 += ks2 + 4u;
  TFR(13) TFR(15) TFR(26) TFR(6)
  x0 += ks2; x1 += k0 + 5u;
#undef TFR
  y0 = x0; y1 = x1;
}

// partitionable random_bits (32-bit): counter = (hi=0, lo=flat), bits = y0^y1
// then uniform(minval=tiny,1) -> gumbel, matching jax gumbel()/uniform() fp32.
DINLINE float gumbel32(uint32_t k0, uint32_t k1, uint32_t flat)
{
  uint32_t b1, b2; tf2x32(k0, k1, 0u, flat, b1, b2);
  const uint32_t bits = b1 ^ b2;
  const float f = __uint_as_float((bits >> 9) | 0x3F800000u) - 1.0f;
  const float u = (f == 0.0f) ? 1.17549435e-38f : f; // max(tiny, f*1+tiny)
  return -logf(-logf(u));
}

DINLINE float sigmoidf_(float x) { return 1.0f / (1.0f + expf(-x)); }

#define PSTRIDE 256   // partials per-row stride (250 tiles, padded)

// ---------------------------------------------------------------------------
// init: zero encoder h0
__global__ void k_init(float* __restrict__ henc0)
{
  const int i = blockIdx.x * 256 + threadIdx.x;
  if (i < 1024) henc0[i] = 0.0f;
}

// ---------------------------------------------------------------------------
// Encoder: xg[s*2+b][g] = emb_src[src[s][b]] @ Wex + be   (48 x 1536, K=512)
__global__ __launch_bounds__(256) void k_enc_xg(
    const int* __restrict__ src, const float* __restrict__ emb,
    const float* __restrict__ Wex, const float* __restrict__ be,
    float* __restrict__ xg)
{
  __shared__ float xl[512];
  const int rrow = blockIdx.x;         // s*2+b
  const int tid = threadIdx.x;
  const int tokv = src[rrow];
  for (int i = tid; i < 512; i += 256) xl[i] = emb[(size_t)tokv * 512 + i];
  __syncthreads();
  const int j = blockIdx.y * 256 + tid;
  float a = be[j];
  for (int k = 0; k < 512; ++k) a += xl[k] * Wex[(size_t)k * 1536 + j];
  xg[(size_t)rrow * 1536 + j] = a;
}

// Encoder recurrent step: hout = GRU(x_s, hprev). grid(4) x 256, 2 rows x 128 j.
__global__ __launch_bounds__(256) void k_enc_step(
    const float* __restrict__ hprev, const float* __restrict__ xg,
    const float* __restrict__ Weh, float* __restrict__ hout)
{
  __shared__ float hp[2][512];
  const int tid = threadIdx.x;
  for (int i = tid; i < 1024; i += 256) hp[i >> 9][i & 511] = hprev[i];
  __syncthreads();
  const int row = tid >> 7;                       // 0..1
  const int j = blockIdx.x * 128 + (tid & 127);   // 0..511
  float gz = 0.f, gr = 0.f, gn = 0.f;
  for (int k = 0; k < 512; ++k) {
    const float h = hp[row][k];
    const float* w = Weh + (size_t)k * 1536 + j;
    gz += h * w[0]; gr += h * w[512]; gn += h * w[1024];
  }
  const float xz = xg[row * 1536 + j];
  const float xr = xg[row * 1536 + j + 512];
  const float xn = xg[row * 1536 + j + 1024];
  const float z = sigmoidf_(xz + gz);
  const float r = sigmoidf_(xr + gr);
  const float n = tanhf(xn + r * gn);
  hout[row * 512 + j] = (1.0f - z) * n + z * hp[row][j];
}

// Decoder state init: h = repeat(hT), tok=BOS, dead=0, acc=0, match=1 (BOS hit)
__global__ void k_dec_init(const float* __restrict__ ctx23, float* __restrict__ hA,
                           int* __restrict__ tok, float* __restrict__ dead,
                           float* __restrict__ acc, int* __restrict__ mc)
{
  const int i = blockIdx.x * 256 + threadIdx.x;
  if (i < 200 * 512) {
    const int bn = i >> 9, k = i & 511, b = bn / 100;
    hA[i] = ctx23[b * 512 + k];
  }
  if (i < 200) { tok[i] = 2; dead[i] = 0.f; acc[i] = 0.f; mc[i] = 1; }
}

// ---------------------------------------------------------------------------
// gates GEMM: z=0 -> gx = emb_tgt[tok] @ Wdx + bd ; z=1 -> gh = h @ Wdh
// tiles 32x32, BK=32, 2x2 microtile. grid(48, 7, 2) x 256.
__global__ __launch_bounds__(256) void k_gates(
    const float* __restrict__ hprev, const float* __restrict__ emb_tgt,
    const int* __restrict__ tok,
    const float* __restrict__ Wdx, const float* __restrict__ Wdh,
    const float* __restrict__ bd,
    float* __restrict__ gx, float* __restrict__ gh)
{
  __shared__ float As[32][33];
  __shared__ float Ws[32][32];
  const int tid = threadIdx.x;
  const int nt = blockIdx.x, mt = blockIdx.y, zz = blockIdx.z;
  const int c0 = nt * 32;
  const float* __restrict__ Bw = zz ? Wdh : Wdx;
  float a00 = 0.f, a01 = 0.f, a10 = 0.f, a11 = 0.f;
  const int tr = tid >> 4, tc = tid & 15;
  for (int k0 = 0; k0 < 512; k0 += 32) {
    {
      const int r = tid >> 3, kk = (tid & 7) << 2;
      const int row = mt * 32 + r;
      float4 v = make_float4(0.f, 0.f, 0.f, 0.f);
      if (row < 200) {
        const int k = k0 + kk;
        if (zz == 0) v = *(const float4*)(emb_tgt + (size_t)tok[row] * 512 + k);
        else         v = *(const float4*)(hprev + (size_t)row * 512 + k);
      }
      As[kk + 0][r] = v.x; As[kk + 1][r] = v.y; As[kk + 2][r] = v.z; As[kk + 3][r] = v.w;
    }
    {
      const int kr = tid >> 3, cc = (tid & 7) << 2;
      *(float4*)&Ws[kr][cc] = *(const float4*)(Bw + (size_t)(k0 + kr) * 1536 + c0 + cc);
    }
    __syncthreads();
#pragma unroll
    for (int kk = 0; kk < 32; ++kk) {
      const float a0 = As[kk][tr * 2], a1 = As[kk][tr * 2 + 1];
      const float w0 = Ws[kk][tc * 2], w1 = Ws[kk][tc * 2 + 1];
      a00 += a0 * w0; a01 += a0 * w1; a10 += a1 * w0; a11 += a1 * w1;
    }
    __syncthreads();
  }
  float* __restrict__ outp = zz ? gh : gx;
  const int row0 = mt * 32 + tr * 2, col0 = c0 + tc * 2;
  const float b0 = zz ? 0.f : bd[col0];
  const float b1 = zz ? 0.f : bd[col0 + 1];
  if (row0 < 200) {
    outp[(size_t)row0 * 1536 + col0]     = a00 + b0;
    outp[(size_t)row0 * 1536 + col0 + 1] = a01 + b1;
  }
  if (row0 + 1 < 200) {
    outp[(size_t)(row0 + 1) * 1536 + col0]     = a10 + b0;
    outp[(size_t)(row0 + 1) * 1536 + col0 + 1] = a11 + b1;
  }
}

// ---------------------------------------------------------------------------
// Per-row: GRU combine -> h_t, then attention softmax over S=24 -> context c.
// grid(200) x 256.
__global__ __launch_bounds__(256) void k_update_attn(
    const float* __restrict__ gx, const float* __restrict__ gh,
    const float* __restrict__ hprev, float* __restrict__ hcur,
    const float* __restrict__ ctx, const int* __restrict__ src,
    float* __restrict__ cc)
{
  const int bn = blockIdx.x, b = bn / 100;
  const int tid = threadIdx.x;
  __shared__ float hn[512];
  __shared__ float sc[24];
  const float* gxr = gx + (size_t)bn * 1536;
  const float* ghr = gh + (size_t)bn * 1536;
  const float* hpr = hprev + (size_t)bn * 512;
  for (int j = tid; j < 512; j += 256) {
    const float z = sigmoidf_(gxr[j] + ghr[j]);
    const float r = sigmoidf_(gxr[j + 512] + ghr[j + 512]);
    const float n = tanhf(gxr[j + 1024] + r * ghr[j + 1024]);
    const float h = (1.0f - z) * n + z * hpr[j];
    hn[j] = h;
    hcur[(size_t)bn * 512 + j] = h;
  }
  __syncthreads();
  const int w = tid >> 6, lane = tid & 63;
  for (int s = w; s < 24; s += 4) {
    const float* cr = ctx + (size_t)(s * 2 + b) * 512;
    float v = 0.f;
#pragma unroll
    for (int m = 0; m < 8; ++m) { const int k = lane + 64 * m; v += hn[k] * cr[k]; }
#pragma unroll
    for (int m2 = 32; m2 >= 1; m2 >>= 1) v += __shfl_xor(v, m2, 64);
    if (lane == 0) sc[s] = (src[s * 2 + b] == 0) ? -1e9f : v;  // pad mask (NEG_INF)
  }
  __syncthreads();
  float mx = -3.0e38f;
#pragma unroll
  for (int s = 0; s < 24; ++s) mx = fmaxf(mx, sc[s]);
  float ez[24]; float sum = 0.f;
#pragma unroll
  for (int s = 0; s < 24; ++s) { ez[s] = expf(sc[s] - mx); sum += ez[s]; }
#pragma unroll
  for (int s = 0; s < 24; ++s) ez[s] = ez[s] / sum;  // attn, rounded like reference
  for (int j = tid; j < 512; j += 256) {
    float a = 0.f;
#pragma unroll
    for (int s = 0; s < 24; ++s) a += ez[s] * ctx[(size_t)(s * 2 + b) * 512 + j];
    cc[(size_t)bn * 512 + j] = a;
  }
}

// ---------------------------------------------------------------------------
// o = tanh([h|c] @ Wo + bo). 16x32 tiles, K=1024, 2 outputs/thread.
// grid(16, 13) x 256 = 208 blocks (was 112; occupancy fix).
// Per-output accumulation is strictly k-ascending in one fp32 acc ->
// bit-identical to the r4 version (retile changes no arithmetic).
__global__ __launch_bounds__(256) void k_oproj(
    const float* __restrict__ hcur, const float* __restrict__ ccx,
    const float* __restrict__ Wo, const float* __restrict__ bo,
    float* __restrict__ ob)
{
  __shared__ float As[32][17];   // [kk][row], 17 stride: conflict-free
  __shared__ float Ws[32][32];   // [kk][col]
  const int tid = threadIdx.x;
  const int nt = blockIdx.x, mt = blockIdx.y;
  const int c0 = nt * 32, r0 = mt * 16;
  const int tr = tid >> 4, tc = tid & 15;      // row 0..15, col-pair 0..15
  float a0 = 0.f, a1 = 0.f;
  for (int k0 = 0; k0 < 1024; k0 += 32) {
    {
      const int kk = tid & 31;                 // 0..31
      const int rr = tid >> 5;                 // 0..7
      const int k = k0 + kk;
      const float* srcp = (k < 512) ? (hcur + k) : (ccx + (k - 512));
      for (int r = rr; r < 16; r += 8) {
        const int row = r0 + r;
        As[kk][r] = (row < 200) ? srcp[(size_t)row * 512] : 0.f;
      }
    }
    {
      const int kr = tid >> 3, cc = (tid & 7) << 2;
      *(float4*)&Ws[kr][cc] = *(const float4*)(Wo + (size_t)(k0 + kr) * 512 + c0 + cc);
    }
    __syncthreads();
#pragma unroll
    for (int kk = 0; kk < 32; ++kk) {
      const float a = As[kk][tr];
      a0 += a * Ws[kk][tc * 2];
      a1 += a * Ws[kk][tc * 2 + 1];
    }
    __syncthreads();
  }
  const int row = r0 + tr, col = c0 + tc * 2;
  if (row < 200) {
    ob[(size_t)row * 512 + col]     = tanhf(a0 + bo[col]);
    ob[(size_t)row * 512 + col + 1] = tanhf(a1 + bo[col + 1]);
  }
}

// ---------------------------------------------------------------------------
// logits = o @ Wg + bg, fused gumbel + per-tile argmax / max / sumexp partials.
// tiles 64x64, BK=32, 4x4 microtile. grid(250, 4) x 256. Never stores logits.
// UNCHANGED arithmetic vs r4 (token-exactness anchor); only the partial-store
// layout moved to bn-major [row*PSTRIDE + nt] for the parallel reducer.
__global__ __launch_bounds__(256) void k_gemm_logits(
    const float* __restrict__ Ao, const float* __restrict__ Wg,
    const float* __restrict__ bg, int t,
    float* __restrict__ p_bv, float* __restrict__ p_bl,
    float* __restrict__ p_ml, float* __restrict__ p_se, int* __restrict__ p_bi)
{
  __shared__ float As[32][68];
  __shared__ float Ws[32][64];
  const int tid = threadIdx.x;
  const int nt = blockIdx.x, mt = blockIdx.y;
  const int c0 = nt * 64;
  float acc[4][4] = {};
  const int tr = tid >> 4, tc = tid & 15;
  for (int k0 = 0; k0 < 512; k0 += 32) {
    {
      const int r = tid >> 2, kk = (tid & 3) << 3;
      const int row = mt * 64 + r;
      float4 v0 = make_float4(0.f, 0.f, 0.f, 0.f), v1 = v0;
      if (row < 200) {
        const float* s = Ao + (size_t)row * 512 + k0 + kk;
        v0 = *(const float4*)s; v1 = *(const float4*)(s + 4);
      }
      As[kk + 0][r] = v0.x; As[kk + 1][r] = v0.y; As[kk + 2][r] = v0.z; As[kk + 3][r] = v0.w;
      As[kk + 4][r] = v1.x; As[kk + 5][r] = v1.y; As[kk + 6][r] = v1.z; As[kk + 7][r] = v1.w;
    }
    {
      const int kr = tid >> 3, cc = (tid & 7) << 3;
      const float* s = Wg + (size_t)(k0 + kr) * 16000 + c0 + cc;
      *(float4*)&Ws[kr][cc]     = *(const float4*)s;
      *(float4*)&Ws[kr][cc + 4] = *(const float4*)(s + 4);
    }
    __syncthreads();
#pragma unroll
    for (int kk = 0; kk < 32; ++kk) {
      const float4 a = *(const float4*)&As[kk][tr << 2];
      const float4 w = *(const float4*)&Ws[kk][tc << 2];
      acc[0][0] += a.x * w.x; acc[0][1] += a.x * w.y; acc[0][2] += a.x * w.z; acc[0][3] += a.x * w.w;
      acc[1][0] += a.y * w.x; acc[1][1] += a.y * w.y; acc[1][2] += a.y * w.z; acc[1][3] += a.y * w.w;
      acc[2][0] += a.z * w.x; acc[2][1] += a.z * w.y; acc[2][2] += a.z * w.z; acc[2][3] += a.z * w.w;
      acc[3][0] += a.w * w.x; acc[3][1] += a.w * w.y; acc[3][2] += a.w * w.z; acc[3][3] += a.w * w.w;
    }
    __syncthreads();
  }
  // epilogue: gumbel + per-row tile reductions over the 64-col tile
  uint32_t sk0, sk1; tf2x32(0u, 42u, 0u, (uint32_t)t, sk0, sk1); // split(key(42))[t]
  const float NEGINF = -3.0e38f;
#pragma unroll
  for (int i = 0; i < 4; ++i) {
    const int row = mt * 64 + (tr << 2) + i;
    const bool valid = (row < 200);
    float logit[4];
    float tmax = NEGINF;
#pragma unroll
    for (int j = 0; j < 4; ++j) {
      const int col = c0 + (tc << 2) + j;
      logit[j] = acc[i][j] + bg[col];
      tmax = fmaxf(tmax, logit[j]);
    }
    if (!valid) tmax = NEGINF;
#pragma unroll
    for (int m = 1; m <= 8; m <<= 1) tmax = fmaxf(tmax, __shfl_xor(tmax, m, 64));
    float se = 0.f, bv = NEGINF, bl = 0.f; int bi = 0;
    if (valid) {
#pragma unroll
      for (int j = 0; j < 4; ++j) {
        const int col = c0 + (tc << 2) + j;
        se += expf(logit[j] - tmax);
        const float g = gumbel32(sk0, sk1, (uint32_t)(row * 16000 + col));
        const float v = logit[j] + g;
        if (v > bv) { bv = v; bi = col; bl = logit[j]; }  // first-occurrence ties
      }
    }
#pragma unroll
    for (int m = 1; m <= 8; m <<= 1) {
      const float ov = __shfl_xor(bv, m, 64);
      const int   oi = __shfl_xor(bi, m, 64);
      const float ol = __shfl_xor(bl, m, 64);
      se += __shfl_xor(se, m, 64);
      if (ov > bv || (ov == bv && oi < bi)) { bv = ov; bi = oi; bl = ol; }
    }
    if (tc == 0 && valid) {
      const size_t p = (size_t)row * PSTRIDE + nt;   // bn-major for coalesced reduce
      p_bv[p] = bv; p_bl[p] = bl; p_ml[p] = tmax; p_se[p] = se; p_bi[p] = bi;
    }
  }
}

// ---------------------------------------------------------------------------
// Parallel combine of 250 tile-partials per row. grid(200) x 64 (one wave/bn).
// Global max M: exact (tree max). Argmax: exact (max + lower-index tie-break,
// associative). Denominator S: tree order (differs from r4's sequential online
// merge by ~1e-7 relative - inside tolerance; discrete path unchanged).
__global__ void k_reduce_sample(
    const float* __restrict__ p_bv, const float* __restrict__ p_bl,
    const float* __restrict__ p_ml, const float* __restrict__ p_se,
    const int* __restrict__ p_bi,
    const int* __restrict__ tgt, int t,
    int* __restrict__ tok, float* __restrict__ dead,
    float* __restrict__ acc, int* __restrict__ mc)
{
  const int bn = blockIdx.x;
  const int lane = threadIdx.x;                 // 0..63
  const size_t base = (size_t)bn * PSTRIDE;
  float M = -3.0e38f;
  for (int nt = lane; nt < 250; nt += 64) M = fmaxf(M, p_ml[base + nt]);
#pragma unroll
  for (int m = 32; m >= 1; m >>= 1) M = fmaxf(M, __shfl_xor(M, m, 64));
  float S = 0.f, bv = -3.0e38f, bl = 0.f;
  int bi = 0x7FFFFFFF;
  for (int nt = lane; nt < 250; nt += 64) {
    S += p_se[base + nt] * expf(p_ml[base + nt] - M);
    const float v = p_bv[base + nt];
    const int   i = p_bi[base + nt];
    if (v > bv || (v == bv && i < bi)) { bv = v; bi = i; bl = p_bl[base + nt]; }
  }
#pragma unroll
  for (int m = 32; m >= 1; m >>= 1) {
    S += __shfl_xor(S, m, 64);
    const float ov = __shfl_xor(bv, m, 64);
    const int   oi = __shfl_xor(bi, m, 64);
    const float ol = __shfl_xor(bl, m, 64);
    if (ov > bv || (ov == bv && oi < bi)) { bv = ov; bi = oi; bl = ol; }
  }
  if (lane == 0) {
    const float dv = dead[bn];
    acc[bn] += ((bl - M) - logf(S)) * (1.0f - dv);   // logp[nxt]*(1-dead)
    const int b = bn / 100;
    if (t + 1 < 26) {
      const int tv = tgt[(t + 1) * 2 + b];
      if (tv != 0 && bi == tv) mc[bn] += 1;
    }
    dead[bn] = fmaxf(dv, (bi == 3) ? 1.0f : 0.0f);   // EOS=3
    tok[bn] = bi;
  }
}

// ---------------------------------------------------------------------------
// Final: bleu, per-batch softmax over N=100 of acc*ALPHA, 4 scalar outputs.
__global__ __launch_bounds__(256) void k_final(
    const float* __restrict__ accb, const int* __restrict__ mc,
    const int* __restrict__ tgt, float* __restrict__ out)
{
  __shared__ int ncw[4];
  __shared__ float LS[2], SS[2], QS[2];
  const int tid = threadIdx.x, w = tid >> 6, lane = tid & 63;
  int c0c = 0, c1c = 0;
  for (int tt = 0; tt < 26; ++tt) {
    c0c += (tgt[tt * 2] != 0);
    c1c += (tgt[tt * 2 + 1] != 0);
  }
  int nc = (tid < 200) ? mc[tid] : 0;
#pragma unroll
  for (int m = 32; m >= 1; m >>= 1) nc += __shfl_xor(nc, m, 64);
  if (lane == 0) ncw[w] = nc;
  if (w < 2) {
    const int b = w;
    const float denom = fmaxf((float)(b == 0 ? c0c : c1c), 1.0f);
    const float e0 = accb[b * 100 + lane] * 0.005f;
    const float e1 = (lane < 36) ? accb[b * 100 + 64 + lane] * 0.005f : -3.0e38f;
    float mx = fmaxf(e0, e1);
#pragma unroll
    for (int m = 32; m >= 1; m >>= 1) mx = fmaxf(mx, __shfl_xor(mx, m, 64));
    float S = 0.f, L = 0.f, Q = 0.f;
    {
      const float p = expf(e0 - mx);
      const float bl = (float)mc[b * 100 + lane] / denom;
      S += p; L += bl * p; Q += bl * bl * p;
    }
    if (lane < 36) {
      const float p = expf(e1 - mx);
      const float bl = (float)mc[b * 100 + 64 + lane] / denom;
      S += p; L += bl * p; Q += bl * bl * p;
    }
#pragma unroll
    for (int m = 32; m >= 1; m >>= 1) {
      S += __shfl_xor(S, m, 64);
      L += __shfl_xor(L, m, 64);
      Q += __shfl_xor(Q, m, 64);
    }
    if (lane == 0) { LS[b] = L; SS[b] = S; QS[b] = Q; }
  }
  __syncthreads();
  if (tid == 0) {
    out[0] = -(LS[0] / SS[0] + LS[1] / SS[1]);  // totalLoss
    out[1] =  QS[0] / SS[0] + QS[1] / SS[1];    // secondMoment
    out[2] = 100.0f * (float)(c0c + c1c);       // numWords
    out[3] = (float)(ncw[0] + ncw[1] + ncw[2] + ncw[3]);  // numCorrect
  }
}

// ---------------------------------------------------------------------------
extern "C" void kernel_launch(void* const* d_in, const int* in_sizes, int n_in,
                              void* d_out, int out_size, void* d_ws, size_t ws_size,
                              hipStream_t stream)
{
  (void)in_sizes; (void)n_in; (void)out_size; (void)ws_size;
  const int*   src     = (const int*)  d_in[0];
  const int*   tgt     = (const int*)  d_in[1];
  // d_in[2] lengths: unused by the reference math
  const float* emb_src = (const float*)d_in[3];
  const float* emb_tgt = (const float*)d_in[4];
  const float* Wex     = (const float*)d_in[5];
  const float* Weh     = (const float*)d_in[6];
  const float* be      = (const float*)d_in[7];
  const float* Wdx     = (const float*)d_in[8];
  const float* Wdh     = (const float*)d_in[9];
  const float* bd      = (const float*)d_in[10];
  const float* Wo      = (const float*)d_in[11];
  const float* bo      = (const float*)d_in[12];
  const float* Wg      = (const float*)d_in[13];
  const float* bg      = (const float*)d_in[14];
  float* out = (float*)d_out;

  float* W = (float*)d_ws;
  size_t off = 0;
  auto alloc = [&](size_t n) { float* p = W + off; off += n; return p; };
  float* henc0 = alloc(1024);
  float* xgE   = alloc(48 * 1536);
  float* ctx   = alloc(24 * 1024);
  float* hA    = alloc(200 * 512);
  float* hB    = alloc(200 * 512);
  float* gx    = alloc(200 * 1536);
  float* gh    = alloc(200 * 1536);
  float* cc    = alloc(200 * 512);
  float* ob    = alloc(200 * 512);
  float* p_bv  = alloc(200 * PSTRIDE);
  float* p_bl  = alloc(200 * PSTRIDE);
  float* p_ml  = alloc(200 * PSTRIDE);
  float* p_se  = alloc(200 * PSTRIDE);
  int*   p_bi  = (int*)alloc(200 * PSTRIDE);
  int*   tok   = (int*)alloc(200);
  float* dead  = alloc(200);
  float* accb  = alloc(200);
  int*   mc    = (int*)alloc(200);
  // total ~5.6 MB of d_ws

  // --- encoder ---
  k_init<<<dim3(4), dim3(256), 0, stream>>>(henc0);
  k_enc_xg<<<dim3(48, 6), dim3(256), 0, stream>>>(src, emb_src, Wex, be, xgE);
  for (int s = 0; s < 24; ++s) {
    const float* hp = (s == 0) ? henc0 : (ctx + (size_t)(s - 1) * 1024);
    k_enc_step<<<dim3(4), dim3(256), 0, stream>>>(
        hp, xgE + (size_t)s * 2 * 1536, Weh, ctx + (size_t)s * 1024);
  }
  k_dec_init<<<dim3(400), dim3(256), 0, stream>>>(ctx + 23 * 1024, hA, tok, dead, accb, mc);

  // --- decoder: 37 sequential sampled steps ---
  for (int t = 0; t < 37; ++t) {
    float* hp = (t & 1) ? hB : hA;
    float* hc = (t & 1) ? hA : hB;
    k_gates<<<dim3(48, 7, 2), dim3(256), 0, stream>>>(hp, emb_tgt, tok, Wdx, Wdh, bd, gx, gh);
    k_update_attn<<<dim3(200), dim3(256), 0, stream>>>(gx, gh, hp, hc, ctx, src, cc);
    k_oproj<<<dim3(16, 13), dim3(256), 0, stream>>>(hc, cc, Wo, bo, ob);
    k_gemm_logits<<<dim3(250, 4), dim3(256), 0, stream>>>(ob, Wg, bg, t,
                                                          p_bv, p_bl, p_ml, p_se, p_bi);
    k_reduce_sample<<<dim3(200), dim3(64), 0, stream>>>(p_bv, p_bl, p_ml, p_se, p_bi,
                                                        tgt, t, tok, dead, accb, mc);
  }
  k_final<<<dim3(1), dim3(256), 0, stream>>>(accb, mc, tgt, out);
}